// Round 1
// baseline (1243.577 us; speedup 1.0000x reference)
//
#include <hip/hip_runtime.h>

#define TSEQ 512
#define HID  64

__device__ __forceinline__ float rl(float v, int lane) {
  return __int_as_float(__builtin_amdgcn_readlane(__float_as_int(v), lane));
}
__device__ __forceinline__ float fast_rcp(float x) { return __builtin_amdgcn_rcpf(x); }
__device__ __forceinline__ float sigm(float x)   { return fast_rcp(1.0f + __expf(-x)); }
__device__ __forceinline__ float tanh_f(float x) { return 1.0f - 2.0f * fast_rcp(__expf(2.0f * x) + 1.0f); }

// One WG (256 thr = 4 waves) owns 4 batch elements for all 512 steps.
// wave w = k-quarter [16w,16w+16); lane j = hidden index; weights live in VGPRs:
// per lane 4 matrices x 4 gate-rows x 16 k = 256 floats.
extern "C" __global__ void __launch_bounds__(256, 1)
lstm_fused(const float* __restrict__ x,
           const float* __restrict__ wih0, const float* __restrict__ whh0,
           const float* __restrict__ bih0, const float* __restrict__ bhh0,
           const float* __restrict__ wih1, const float* __restrict__ whh1,
           const float* __restrict__ bih1, const float* __restrict__ bhh1,
           const float* __restrict__ fcw,  const float* __restrict__ fcb,
           float* __restrict__ out)
{
  __shared__ __align__(16) float part[4096];   // [kq][b][j][gate] float4 per (kq,b,j)
  __shared__ float h0buf[256];                 // [b][j]
  __shared__ float h1buf[256];

  const int tid   = threadIdx.x;
  const int w     = tid >> 6;        // wave index = k-quarter; also owns batch w in cell phases
  const int j     = tid & 63;        // lane = hidden / gate-row index
  const int bl    = (tid >> 4) & 3;  // slice mapping: lane L holds input[b=bl][k=kbase+kl]
  const int kl    = tid & 15;
  const int b0    = blockIdx.x << 2;
  const int kbase = w << 4;

  // ---- load weight slices into registers (one-time) ----
  float Wih0[4][16], Whh0[4][16], Wih1[4][16], Whh1[4][16];
#pragma unroll
  for (int g = 0; g < 4; ++g) {
    const int row = g * 64 + j;
#pragma unroll
    for (int kk = 0; kk < 16; ++kk) {
      const int idx = row * 64 + kbase + kk;
      Wih0[g][kk] = wih0[idx];
      Whh0[g][kk] = whh0[idx];
      Wih1[g][kk] = wih1[idx];
      Whh1[g][kk] = whh1[idx];
    }
  }
  float bias0[4], bias1[4];
#pragma unroll
  for (int g = 0; g < 4; ++g) {
    bias0[g] = bih0[g * 64 + j] + bhh0[g * 64 + j];
    bias1[g] = bih1[g * 64 + j] + bhh1[g * 64 + j];
  }
  const float fw = fcw[j];
  const float fb = fcb[0];

  float c0 = 0.f, c1 = 0.f;
  float hv01 = 0.f;   // slice of layer-0 h (prev step) held as [bl][kbase+kl]
  float hv1  = 0.f;   // slice of layer-1 h (prev step)
  float h1last = 0.f;

  const float* xp = x + (size_t)(b0 + bl) * (TSEQ * 64) + kbase + kl;
  float xv = xp[0];

  for (int t = 0; t < TSEQ; ++t) {
    const int tn = (t + 1 < TSEQ) ? (t + 1) : t;
    const float xnext = xp[tn * 64];          // prefetch next step's x slice

    // ---- phase A: layer-0 gate partials over this wave's k-quarter ----
    float p[4][4];
#pragma unroll
    for (int g = 0; g < 4; ++g)
#pragma unroll
      for (int b = 0; b < 4; ++b) p[g][b] = 0.f;

#pragma unroll
    for (int kk = 0; kk < 16; ++kk) {
#pragma unroll
      for (int b = 0; b < 4; ++b) {
        const float xs = rl(xv,   b * 16 + kk);   // x[b][kbase+kk] (wave-uniform)
        const float hs = rl(hv01, b * 16 + kk);   // h0[b][kbase+kk]
#pragma unroll
        for (int g = 0; g < 4; ++g) {
          p[g][b] = fmaf(xs, Wih0[g][kk], p[g][b]);
          p[g][b] = fmaf(hs, Whh0[g][kk], p[g][b]);
        }
      }
    }
#pragma unroll
    for (int b = 0; b < 4; ++b) {
      float4 v = make_float4(p[0][b], p[1][b], p[2][b], p[3][b]);
      *(float4*)(&part[((w * 4 + b) * 64 + j) * 4]) = v;
    }
    __syncthreads();

    // ---- phase B: layer-0 cell update; wave w handles batch element w ----
    {
      float4 s = *(const float4*)(&part[((0 * 4 + w) * 64 + j) * 4]);
#pragma unroll
      for (int q = 1; q < 4; ++q) {
        float4 v = *(const float4*)(&part[((q * 4 + w) * 64 + j) * 4]);
        s.x += v.x; s.y += v.y; s.z += v.z; s.w += v.w;
      }
      const float gi = sigm(s.x + bias0[0]);
      const float gf = sigm(s.y + bias0[1]);
      const float gg = tanh_f(s.z + bias0[2]);
      const float go = sigm(s.w + bias0[3]);
      c0 = gf * c0 + gi * gg;
      const float h0n = go * tanh_f(c0);
      h0buf[w * 64 + j] = h0n;
    }
    __syncthreads();

    // ---- phase C: layer-1 gate partials (input = h0 of this step) ----
    hv01 = h0buf[bl * 64 + kbase + kl];   // also serves as next step's layer-0 recurrent slice
#pragma unroll
    for (int g = 0; g < 4; ++g)
#pragma unroll
      for (int b = 0; b < 4; ++b) p[g][b] = 0.f;
#pragma unroll
    for (int kk = 0; kk < 16; ++kk) {
#pragma unroll
      for (int b = 0; b < 4; ++b) {
        const float is = rl(hv01, b * 16 + kk);
        const float hs = rl(hv1,  b * 16 + kk);
#pragma unroll
        for (int g = 0; g < 4; ++g) {
          p[g][b] = fmaf(is, Wih1[g][kk], p[g][b]);
          p[g][b] = fmaf(hs, Whh1[g][kk], p[g][b]);
        }
      }
    }
#pragma unroll
    for (int b = 0; b < 4; ++b) {
      float4 v = make_float4(p[0][b], p[1][b], p[2][b], p[3][b]);
      *(float4*)(&part[((w * 4 + b) * 64 + j) * 4]) = v;
    }
    __syncthreads();

    // ---- phase D: layer-1 cell update ----
    {
      float4 s = *(const float4*)(&part[((0 * 4 + w) * 64 + j) * 4]);
#pragma unroll
      for (int q = 1; q < 4; ++q) {
        float4 v = *(const float4*)(&part[((q * 4 + w) * 64 + j) * 4]);
        s.x += v.x; s.y += v.y; s.z += v.z; s.w += v.w;
      }
      const float gi = sigm(s.x + bias1[0]);
      const float gf = sigm(s.y + bias1[1]);
      const float gg = tanh_f(s.z + bias1[2]);
      const float go = sigm(s.w + bias1[3]);
      c1 = gf * c1 + gi * gg;
      const float h1n = go * tanh_f(c1);
      h1buf[w * 64 + j] = h1n;
      h1last = h1n;
    }
    __syncthreads();
    hv1 = h1buf[bl * 64 + kbase + kl];

    xv = xnext;
  }

  // ---- FC head: wave w owns batch b0+w; reduce h1last*fw over 64 lanes ----
  float v = h1last * fw;
#pragma unroll
  for (int off = 32; off > 0; off >>= 1) v += __shfl_xor(v, off);
  if (j == 0) out[b0 + w] = v + fb;
}

extern "C" void kernel_launch(void* const* d_in, const int* in_sizes, int n_in,
                              void* d_out, int out_size, void* d_ws, size_t ws_size,
                              hipStream_t stream) {
  const float* x    = (const float*)d_in[0];
  const float* wih0 = (const float*)d_in[1];
  const float* whh0 = (const float*)d_in[2];
  const float* bih0 = (const float*)d_in[3];
  const float* bhh0 = (const float*)d_in[4];
  const float* wih1 = (const float*)d_in[5];
  const float* whh1 = (const float*)d_in[6];
  const float* bih1 = (const float*)d_in[7];
  const float* bhh1 = (const float*)d_in[8];
  const float* fcw  = (const float*)d_in[9];
  const float* fcb  = (const float*)d_in[10];
  float* out = (float*)d_out;

  hipLaunchKernelGGL(lstm_fused, dim3(256), dim3(256), 0, stream,
                     x, wih0, whh0, bih0, bhh0, wih1, whh1, bih1, bhh1, fcw, fcb, out);
}

// Round 2
// 1130.066 us; speedup vs baseline: 1.1004x; 1.1004x over previous
//
#include <hip/hip_runtime.h>

#define TSEQ 512

typedef __attribute__((ext_vector_type(8))) short short8;   // 8 bf16 (4 VGPRs)
typedef __attribute__((ext_vector_type(4))) float f32x4;

#define MFMA(a,b,c) __builtin_amdgcn_mfma_f32_16x16x32_bf16(a,b,c,0,0,0)

__device__ __forceinline__ float fast_rcp(float x){ return __builtin_amdgcn_rcpf(x); }
__device__ __forceinline__ float sigm(float x){ return fast_rcp(1.0f + __expf(-x)); }
__device__ __forceinline__ float tanh_f(float x){ return 1.0f - 2.0f*fast_rcp(__expf(2.0f*x)+1.0f); }

// round-to-nearest-even bf16; returns bits, outputs the rounded float value
__device__ __forceinline__ short bf16r(float x, float &fv){
  unsigned u = __float_as_uint(x);
  unsigned r = (u + 0x7FFFu + ((u>>16)&1u)) >> 16;
  fv = __uint_as_float(r << 16);
  return (short)r;
}
__device__ __forceinline__ void split(float x, short &h, short &l){
  float hf, dummy;
  h = bf16r(x, hf);
  l = bf16r(x - hf, dummy);
}

// 64 WGs x 1024 threads. WG owns Mb=16 batch rows for all 512 steps.
// Wave w = gate N-tile [16w,16w+16) for BOTH layer GEMMs; weights as hi/lo
// bf16 B-frags in VGPRs. Activations staged in LDS in frag-ordered layout:
// addr_short(m,k) = (k>>3)*136 + m*8 + (k&7)  (pad 128->136 keeps 16B align +
// spreads banks). Lane L frag f reads 16B at ((f*4+(L>>4))*136+(L&15)*8)*2.
// Software pipeline per iter i: P1 = MFMA {gates1(i), gates0(i+1)}; barrier;
// P2 = {cell1(i), cell0(i+1), stage x(i+2)}; barrier.  (2 barriers/step)
extern "C" __global__ void __launch_bounds__(1024)
lstm_mfma(const float* __restrict__ x,
          const float* __restrict__ wih0, const float* __restrict__ whh0,
          const float* __restrict__ bih0, const float* __restrict__ bhh0,
          const float* __restrict__ wih1, const float* __restrict__ whh1,
          const float* __restrict__ bih1, const float* __restrict__ bhh1,
          const float* __restrict__ fcw,  const float* __restrict__ fcb,
          float* __restrict__ out)
{
  __shared__ __align__(16) float gates[2][16*257];   // [gemm][m][n+pad]
  __shared__ __align__(16) short stg[6][1088];       // 0:xh 1:xl 2:h0h 3:h0l 4:h1h 5:h1l

  const int tid = threadIdx.x;
  const int wv  = tid >> 6;          // wave index: N-tile in P1, batch row m in P2
  const int ln  = tid & 63;
  const int lq  = ln >> 4;           // MFMA quad
  const int lr  = ln & 15;           // MFMA row/col-in-tile
  const int wn  = wv << 4;           // N-tile base
  const int b0  = blockIdx.x << 4;
  const int foff  = lq*136 + lr*8;                   // A-frag lane offset (shorts)
  const int sbase = (ln>>3)*136 + wv*8 + (ln&7);     // cell thread's (m=wv,k=ln) slot

#define LDA(arr, f) (*(const short8*)&stg[arr][foff + (f)*544])

  // ---- one-time: weight B-frags (hi/lo), biases, fc ----
  short8 w0h[4], w0l[4], w1h[4], w1l[4];
  const int nrow = wn + lr;          // B-frag: n = lane&15 within tile
#pragma unroll
  for (int F = 0; F < 4; ++F){
    const float* s0 = ((F<2)? wih0 : whh0) + nrow*64 + (F&1)*32 + lq*8;
    const float* s1 = ((F<2)? wih1 : whh1) + nrow*64 + (F&1)*32 + lq*8;
#pragma unroll
    for (int e = 0; e < 8; ++e){
      short hh, ll;
      split(s0[e], hh, ll); w0h[F][e] = hh; w0l[F][e] = ll;
      split(s1[e], hh, ll); w1h[F][e] = hh; w1l[F][e] = ll;
    }
  }
  float b0r[4], b1r[4];
#pragma unroll
  for (int g2 = 0; g2 < 4; ++g2){
    b0r[g2] = bih0[g2*64+ln] + bhh0[g2*64+ln];
    b1r[g2] = bih1[g2*64+ln] + bhh1[g2*64+ln];
  }
  const float fcwv = fcw[ln];
  const float fcb0 = fcb[0];

  const float* xptr = x + (size_t)(b0 + wv) * (TSEQ*64) + ln;

  float c0 = 0.f, c1 = 0.f, h1v = 0.f;

  // ---- prologue: zero h1 stage, stage x(0), prefetch x(1) ----
  for (int idx = tid; idx < 1088; idx += 1024){ stg[4][idx] = 0; stg[5][idx] = 0; }
  {
    float x0 = xptr[0];
    short xh, xl; split(x0, xh, xl);
    stg[0][sbase] = xh; stg[1][sbase] = xl;
  }
  float xv = xptr[64];               // x(1)
  __syncthreads();

  // P1-pre: gates0(0) = x(0)·Wih0^T  (h0_{-1}=0)
  {
    f32x4 acc0 = {0.f,0.f,0.f,0.f};
#pragma unroll
    for (int F = 0; F < 2; ++F){
      short8 ah = LDA(0, F);
      short8 al = LDA(1, F);
      acc0 = MFMA(ah, w0h[F], acc0);
      acc0 = MFMA(al, w0h[F], acc0);
      acc0 = MFMA(ah, w0l[F], acc0);
    }
#pragma unroll
    for (int r2 = 0; r2 < 4; ++r2)
      gates[0][(lq*4+r2)*257 + wn + lr] = acc0[r2];
  }
  __syncthreads();

  // P2-pre: cell0(0) -> h0_0; stage x(1); prefetch x(2)
  {
    const float* g = &gates[0][wv*257];
    float gi = sigm  (g[ln]       + b0r[0]);
    float gf = sigm  (g[ln + 64]  + b0r[1]);
    float gg = tanh_f(g[ln + 128] + b0r[2]);
    float go = sigm  (g[ln + 192] + b0r[3]);
    c0 = gf*c0 + gi*gg;
    float h0v = go * tanh_f(c0);
    short hh, ll; split(h0v, hh, ll);
    stg[2][sbase] = hh; stg[3][sbase] = ll;
    short xh, xl; split(xv, xh, xl);
    stg[0][sbase] = xh; stg[1][sbase] = xl;
    xv = xptr[2*64];
  }
  __syncthreads();

  // ---- main loop ----
  for (int i = 0; i < TSEQ; ++i){
    const bool notlast = (i < TSEQ-1);

    // P1: gates1(i) = [h0_i | h1_{i-1}]·W1^T ; gates0(i+1) = [x(i+1) | h0_i]·W0^T
    f32x4 acc1 = {0.f,0.f,0.f,0.f};
#pragma unroll
    for (int F = 0; F < 4; ++F){
      const int arr = (F < 2) ? 2 : 4;   // h0 then h1
      const int f   = F & 1;
      short8 ah = LDA(arr,   f);
      short8 al = LDA(arr+1, f);
      acc1 = MFMA(ah, w1h[F], acc1);
      acc1 = MFMA(al, w1h[F], acc1);
      acc1 = MFMA(ah, w1l[F], acc1);
    }
    f32x4 acc0 = {0.f,0.f,0.f,0.f};
    if (notlast){
#pragma unroll
      for (int F = 0; F < 4; ++F){
        const int arr = (F < 2) ? 0 : 2; // x then h0
        const int f   = F & 1;
        short8 ah = LDA(arr,   f);
        short8 al = LDA(arr+1, f);
        acc0 = MFMA(ah, w0h[F], acc0);
        acc0 = MFMA(al, w0h[F], acc0);
        acc0 = MFMA(ah, w0l[F], acc0);
      }
    }
#pragma unroll
    for (int r2 = 0; r2 < 4; ++r2)
      gates[1][(lq*4+r2)*257 + wn + lr] = acc1[r2];
    if (notlast){
#pragma unroll
      for (int r2 = 0; r2 < 4; ++r2)
        gates[0][(lq*4+r2)*257 + wn + lr] = acc0[r2];
    }
    __syncthreads();

    // P2: cell1(i); cell0(i+1); stage x(i+2)
    {
      const float* g = &gates[1][wv*257];
      float gi = sigm  (g[ln]       + b1r[0]);
      float gf = sigm  (g[ln + 64]  + b1r[1]);
      float gg = tanh_f(g[ln + 128] + b1r[2]);
      float go = sigm  (g[ln + 192] + b1r[3]);
      c1 = gf*c1 + gi*gg;
      h1v = go * tanh_f(c1);
      short hh, ll; split(h1v, hh, ll);
      stg[4][sbase] = hh; stg[5][sbase] = ll;
    }
    if (notlast){
      const float* g = &gates[0][wv*257];
      float gi = sigm  (g[ln]       + b0r[0]);
      float gf = sigm  (g[ln + 64]  + b0r[1]);
      float gg = tanh_f(g[ln + 128] + b0r[2]);
      float go = sigm  (g[ln + 192] + b0r[3]);
      c0 = gf*c0 + gi*gg;
      float h0v = go * tanh_f(c0);
      short hh, ll; split(h0v, hh, ll);
      stg[2][sbase] = hh; stg[3][sbase] = ll;
      if (i <= TSEQ-3){
        short xh, xl; split(xv, xh, xl);
        stg[0][sbase] = xh; stg[1][sbase] = xl;
      }
      const int tnext = (i+3 > TSEQ-1) ? (TSEQ-1) : (i+3);
      xv = xptr[tnext << 6];
    }
    __syncthreads();
  }

  // ---- FC head: wave wv owns batch b0+wv; reduce h1v*fcw over 64 lanes ----
  float v = h1v * fcwv;
#pragma unroll
  for (int off = 32; off > 0; off >>= 1) v += __shfl_xor(v, off);
  if (ln == 0) out[b0 + wv] = v + fcb0;
}

extern "C" void kernel_launch(void* const* d_in, const int* in_sizes, int n_in,
                              void* d_out, int out_size, void* d_ws, size_t ws_size,
                              hipStream_t stream) {
  const float* x    = (const float*)d_in[0];
  const float* wih0 = (const float*)d_in[1];
  const float* whh0 = (const float*)d_in[2];
  const float* bih0 = (const float*)d_in[3];
  const float* bhh0 = (const float*)d_in[4];
  const float* wih1 = (const float*)d_in[5];
  const float* whh1 = (const float*)d_in[6];
  const float* bih1 = (const float*)d_in[7];
  const float* bhh1 = (const float*)d_in[8];
  const float* fcw  = (const float*)d_in[9];
  const float* fcb  = (const float*)d_in[10];
  float* out = (float*)d_out;

  hipLaunchKernelGGL(lstm_mfma, dim3(64), dim3(1024), 0, stream,
                     x, wih0, whh0, bih0, bhh0, wih1, whh1, bih1, bhh1, fcw, fcb, out);
}

// Round 3
// 930.888 us; speedup vs baseline: 1.3359x; 1.2140x over previous
//
#include <hip/hip_runtime.h>

#define TSEQ 512

typedef __attribute__((ext_vector_type(8))) short short8;
typedef __attribute__((ext_vector_type(4))) float f32x4;

#define MFMA16(a,b,c) __builtin_amdgcn_mfma_f32_16x16x32_bf16(a,b,c,0,0,0)

union S8U { short8 s; uint4 u; };

static __device__ __forceinline__ float sigm(float x){ return __builtin_amdgcn_rcpf(1.0f + __expf(-x)); }
static __device__ __forceinline__ float tanh_f(float x){ return 1.0f - 2.0f*__builtin_amdgcn_rcpf(__expf(2.0f*x)+1.0f); }

static __device__ __forceinline__ unsigned bf16h(unsigned u){ return (u + 0x7FFFu + ((u>>16)&1u)) >> 16; }

// pack float -> (bf16 hi | bf16 lo<<16) in one dword
static __device__ __forceinline__ unsigned pack_pair(float v){
  unsigned hi = bf16h(__float_as_uint(v));
  float r = v - __uint_as_float(hi<<16);
  unsigned lo = bf16h(__float_as_uint(r));
  return (hi & 0xFFFFu) | (lo<<16);
}
static __device__ __forceinline__ void wsplit(float v, short &h, short &l){
  unsigned hi = bf16h(__float_as_uint(v));
  float r = v - __uint_as_float(hi<<16);
  unsigned lo = bf16h(__float_as_uint(r));
  h = (short)hi; l = (short)lo;
}

// two b128 pair-reads -> hi frag + lo frag (8 v_perm_b32)
static __device__ __forceinline__ void unpack_frag(uint4 p0, uint4 p1, short8 &ah, short8 &al){
  S8U A, L;
  A.u.x = __builtin_amdgcn_perm(p0.y, p0.x, 0x05040100u);
  A.u.y = __builtin_amdgcn_perm(p0.w, p0.z, 0x05040100u);
  A.u.z = __builtin_amdgcn_perm(p1.y, p1.x, 0x05040100u);
  A.u.w = __builtin_amdgcn_perm(p1.w, p1.z, 0x05040100u);
  L.u.x = __builtin_amdgcn_perm(p0.y, p0.x, 0x07060302u);
  L.u.y = __builtin_amdgcn_perm(p0.w, p0.z, 0x07060302u);
  L.u.z = __builtin_amdgcn_perm(p1.y, p1.x, 0x07060302u);
  L.u.w = __builtin_amdgcn_perm(p1.w, p1.z, 0x07060302u);
  ah = A.s; al = L.s;
}

// pair-array dword index for activation element (k, m); XOR-swizzled so both
// the frag-ordered b128 reads and the cell-phase b32 writes are <=2-way.
static __device__ __forceinline__ int pidx(int k, int m){
  int f = k >> 5, lqk = (k>>3)&3, jj = k&7, h = jj>>2;
  int L = lqk*16 + m;
  int s = L ^ (L>>4);
  return f*512 + h*256 + (s ^ (h<<2))*4 + (jj&3);
}

// 256 WGs x 256 thr (4 waves). WG owns batch rows [4*blk, 4*blk+4).
// Wave w: MFMA tiles q=0..3 covering gate cols n = q*64 + 16w + lr, both gemms.
// Weights (3-term bf16 hi/lo B-frags) in VGPRs: 256 regs. 1 wave/SIMD.
// Pipeline per iter i: P1 MFMA {gates1(i), gates0(i+1)}; barrier;
// P2 {cell1(i)->h1, cell0(i+1)->h0, stage x(i+2)}; barrier.
extern "C" __global__ void __launch_bounds__(256, 1)
lstm_mfma4(const float* __restrict__ x,
           const float* __restrict__ wih0, const float* __restrict__ whh0,
           const float* __restrict__ bih0, const float* __restrict__ bhh0,
           const float* __restrict__ wih1, const float* __restrict__ whh1,
           const float* __restrict__ bih1, const float* __restrict__ bhh1,
           const float* __restrict__ fcw,  const float* __restrict__ fcb,
           float* __restrict__ out)
{
  __shared__ __align__(16) unsigned xP[1024], h0P[1024], h1P[1024]; // pair arrays
  __shared__ __align__(16) float g0b[1280], g1b[1280];              // [j*20 + g*4 + m]
  __shared__ float fcpart[16];

  const int tid = threadIdx.x;
  const int wv  = tid >> 6;
  const int ln  = tid & 63;
  const int lq  = ln >> 4;
  const int lr  = ln & 15;
  const int b0  = blockIdx.x << 2;
  const int sA  = ln ^ (ln >> 4);          // reader swizzle
  const int mrow = ln >> 4;                // cell-phase batch row (0..3)
  const int jcol = (wv << 4) + lr;         // cell-phase hidden index (0..63)

  // ---- one-time: weight B-frags hi/lo into VGPRs ----
  short8 w0h[4][4], w0l[4][4], w1h[4][4], w1l[4][4];   // [F chunk][q tile]
#pragma unroll
  for (int F = 0; F < 4; ++F){
    const float* s0 = (F < 2) ? wih0 : whh0;
    const float* s1 = (F < 2) ? wih1 : whh1;
    const int kof = (F & 1)*32 + lq*8;
#pragma unroll
    for (int q = 0; q < 4; ++q){
      const int row = q*64 + (wv<<4) + lr;
#pragma unroll
      for (int e = 0; e < 8; ++e){
        short hh, ll;
        wsplit(s0[row*64 + kof + e], hh, ll); w0h[F][q][e]=hh; w0l[F][q][e]=ll;
        wsplit(s1[row*64 + kof + e], hh, ll); w1h[F][q][e]=hh; w1l[F][q][e]=ll;
      }
    }
  }
  float b0r[4], b1r[4];
#pragma unroll
  for (int g = 0; g < 4; ++g){
    b0r[g] = bih0[g*64 + jcol] + bhh0[g*64 + jcol];
    b1r[g] = bih1[g*64 + jcol] + bhh1[g*64 + jcol];
  }
  const float fcwv = fcw[jcol];
  const float fcb0 = fcb[0];

  const float* xq = x + (size_t)(b0 + mrow)*(TSEQ*64) + jcol;

  float c0 = 0.f, c1 = 0.f, h1v = 0.f;

  // ---- prologue: zero pair arrays; stage x(0); prefetch x(1) ----
  for (int idx = tid; idx < 1024; idx += 256){ xP[idx]=0; h0P[idx]=0; h1P[idx]=0; }
  __syncthreads();
  xP[pidx(jcol, mrow)] = pack_pair(xq[0]);
  float xv = xq[64];                        // x(1)
  __syncthreads();

  // P1-pre: gates0(0) = x(0)·Wih0^T (h0(-1)=0, skip F2,3)
  {
    short8 xh[2], xl[2];
#pragma unroll
    for (int f = 0; f < 2; ++f){
      uint4 p0 = *(const uint4*)&xP[f*512 + sA*4];
      uint4 p1 = *(const uint4*)&xP[f*512 + 256 + (sA^4)*4];
      unpack_frag(p0, p1, xh[f], xl[f]);
    }
    f32x4 a0[4] = {{0,0,0,0},{0,0,0,0},{0,0,0,0},{0,0,0,0}};
#pragma unroll
    for (int F = 0; F < 2; ++F){
#pragma unroll
      for (int q = 0; q < 4; ++q) a0[q] = MFMA16(xh[F], w0h[F][q], a0[q]);
#pragma unroll
      for (int q = 0; q < 4; ++q) a0[q] = MFMA16(xl[F], w0h[F][q], a0[q]);
#pragma unroll
      for (int q = 0; q < 4; ++q) a0[q] = MFMA16(xh[F], w0l[F][q], a0[q]);
    }
    if (lq == 0){
#pragma unroll
      for (int q = 0; q < 4; ++q)
        *(float4*)&g0b[((wv<<4)+lr)*20 + q*4] = make_float4(a0[q][0],a0[q][1],a0[q][2],a0[q][3]);
    }
  }
  __syncthreads();

  // P2-pre: cell0(0) -> h0(0); stage x(1); prefetch x(2)
  {
    float gi = sigm  (g0b[jcol*20 + 0 + mrow] + b0r[0]);
    float gf = sigm  (g0b[jcol*20 + 4 + mrow] + b0r[1]);
    float gg = tanh_f(g0b[jcol*20 + 8 + mrow] + b0r[2]);
    float go = sigm  (g0b[jcol*20 +12 + mrow] + b0r[3]);
    c0 = gi*gg;                      // f*0 + i*g
    float h0v = go * tanh_f(c0);
    h0P[pidx(jcol, mrow)] = pack_pair(h0v);
    xP [pidx(jcol, mrow)] = pack_pair(xv);
    xv = xq[2*64];
  }
  __syncthreads();

  // ---- main loop ----
  for (int i = 0; i < TSEQ; ++i){
    const bool notlast = (i < TSEQ-1);

    // P1: read frags
    short8 h0h[2], h0l[2], h1h[2], h1l[2], xh[2], xl[2];
#pragma unroll
    for (int f = 0; f < 2; ++f){
      uint4 p0 = *(const uint4*)&h0P[f*512 + sA*4];
      uint4 p1 = *(const uint4*)&h0P[f*512 + 256 + (sA^4)*4];
      unpack_frag(p0, p1, h0h[f], h0l[f]);
      uint4 q0 = *(const uint4*)&h1P[f*512 + sA*4];
      uint4 q1 = *(const uint4*)&h1P[f*512 + 256 + (sA^4)*4];
      unpack_frag(q0, q1, h1h[f], h1l[f]);
    }
    if (notlast){
#pragma unroll
      for (int f = 0; f < 2; ++f){
        uint4 p0 = *(const uint4*)&xP[f*512 + sA*4];
        uint4 p1 = *(const uint4*)&xP[f*512 + 256 + (sA^4)*4];
        unpack_frag(p0, p1, xh[f], xl[f]);
      }
    }

    // gemm1: gates1(i) = [h0(i) | h1(i-1)] · W1^T
    f32x4 a1[4] = {{0,0,0,0},{0,0,0,0},{0,0,0,0},{0,0,0,0}};
#pragma unroll
    for (int F = 0; F < 4; ++F){
      short8 Ah = (F < 2) ? h0h[F] : h1h[F-2];
      short8 Al = (F < 2) ? h0l[F] : h1l[F-2];
#pragma unroll
      for (int q = 0; q < 4; ++q) a1[q] = MFMA16(Ah, w1h[F][q], a1[q]);
#pragma unroll
      for (int q = 0; q < 4; ++q) a1[q] = MFMA16(Al, w1h[F][q], a1[q]);
#pragma unroll
      for (int q = 0; q < 4; ++q) a1[q] = MFMA16(Ah, w1l[F][q], a1[q]);
    }
    // gemm0: gates0(i+1) = [x(i+1) | h0(i)] · W0^T
    f32x4 a0[4] = {{0,0,0,0},{0,0,0,0},{0,0,0,0},{0,0,0,0}};
    if (notlast){
#pragma unroll
      for (int F = 0; F < 4; ++F){
        short8 Ah = (F < 2) ? xh[F] : h0h[F-2];
        short8 Al = (F < 2) ? xl[F] : h0l[F-2];
#pragma unroll
        for (int q = 0; q < 4; ++q) a0[q] = MFMA16(Ah, w0h[F][q], a0[q]);
#pragma unroll
        for (int q = 0; q < 4; ++q) a0[q] = MFMA16(Al, w0h[F][q], a0[q]);
#pragma unroll
        for (int q = 0; q < 4; ++q) a0[q] = MFMA16(Ah, w0l[F][q], a0[q]);
      }
    }
    if (lq == 0){
      const int gbase = ((wv<<4)+lr)*20;
#pragma unroll
      for (int q = 0; q < 4; ++q)
        *(float4*)&g1b[gbase + q*4] = make_float4(a1[q][0],a1[q][1],a1[q][2],a1[q][3]);
      if (notlast){
#pragma unroll
        for (int q = 0; q < 4; ++q)
          *(float4*)&g0b[gbase + q*4] = make_float4(a0[q][0],a0[q][1],a0[q][2],a0[q][3]);
      }
    }
    __syncthreads();

    // P2: cell1(i)
    {
      float gi = sigm  (g1b[jcol*20 + 0 + mrow] + b1r[0]);
      float gf = sigm  (g1b[jcol*20 + 4 + mrow] + b1r[1]);
      float gg = tanh_f(g1b[jcol*20 + 8 + mrow] + b1r[2]);
      float go = sigm  (g1b[jcol*20 +12 + mrow] + b1r[3]);
      c1 = gf*c1 + gi*gg;
      h1v = go * tanh_f(c1);
      h1P[pidx(jcol, mrow)] = pack_pair(h1v);
    }
    if (notlast){
      float gi = sigm  (g0b[jcol*20 + 0 + mrow] + b0r[0]);
      float gf = sigm  (g0b[jcol*20 + 4 + mrow] + b0r[1]);
      float gg = tanh_f(g0b[jcol*20 + 8 + mrow] + b0r[2]);
      float go = sigm  (g0b[jcol*20 +12 + mrow] + b0r[3]);
      c0 = gf*c0 + gi*gg;
      float h0v = go * tanh_f(c0);
      h0P[pidx(jcol, mrow)] = pack_pair(h0v);
      if (i < TSEQ-2) xP[pidx(jcol, mrow)] = pack_pair(xv);
      const int tn = (i+3 > TSEQ-1) ? (TSEQ-1) : (i+3);
      xv = xq[tn << 6];
    }
    __syncthreads();
  }

  // ---- FC head ----
  float v = h1v * fcwv;
#pragma unroll
  for (int off = 1; off < 16; off <<= 1) v += __shfl_xor(v, off);
  if (lr == 0) fcpart[wv*4 + mrow] = v;
  __syncthreads();
  if (tid < 4)
    out[b0 + tid] = fcpart[tid] + fcpart[4+tid] + fcpart[8+tid] + fcpart[12+tid] + fcb0;
}

extern "C" void kernel_launch(void* const* d_in, const int* in_sizes, int n_in,
                              void* d_out, int out_size, void* d_ws, size_t ws_size,
                              hipStream_t stream) {
  const float* x    = (const float*)d_in[0];
  const float* wih0 = (const float*)d_in[1];
  const float* whh0 = (const float*)d_in[2];
  const float* bih0 = (const float*)d_in[3];
  const float* bhh0 = (const float*)d_in[4];
  const float* wih1 = (const float*)d_in[5];
  const float* whh1 = (const float*)d_in[6];
  const float* bih1 = (const float*)d_in[7];
  const float* bhh1 = (const float*)d_in[8];
  const float* fcw  = (const float*)d_in[9];
  const float* fcb  = (const float*)d_in[10];
  float* out = (float*)d_out;

  hipLaunchKernelGGL(lstm_mfma4, dim3(256), dim3(256), 0, stream,
                     x, wih0, whh0, bih0, bhh0, wih1, whh1, bih1, bhh1, fcw, fcb, out);
}

// Round 4
// 722.316 us; speedup vs baseline: 1.7217x; 1.2888x over previous
//
#include <hip/hip_runtime.h>

#define TSEQ 512

typedef __attribute__((ext_vector_type(8))) short short8;
typedef __attribute__((ext_vector_type(4))) float f32x4;

#define MFMA16(a,b,c) __builtin_amdgcn_mfma_f32_16x16x32_bf16(a,b,c,0,0,0)

static __device__ __forceinline__ float sigm(float x){ return __builtin_amdgcn_rcpf(1.0f + __expf(-x)); }
static __device__ __forceinline__ float tanh_f(float x){ return 1.0f - 2.0f*__builtin_amdgcn_rcpf(__expf(2.0f*x)+1.0f); }
static __device__ __forceinline__ unsigned bf16h(unsigned u){ return (u + 0x7FFFu + ((u>>16)&1u)) >> 16; }
static __device__ __forceinline__ void fsplit(float v, short &h, short &l){
  unsigned hi = bf16h(__float_as_uint(v));
  float r = v - __uint_as_float(hi << 16);
  h = (short)hi; l = (short)bf16h(__float_as_uint(r));
}

// A-frag masked read: only lanes lr<4 carry real rows (M=4); others zero.
// arr layout: idx(F,kq,m,e) = ((F*4+kq)*4+m)*8+e, k = F*32+kq*8+e.
static __device__ __forceinline__ short8 ldfrag(const short* arr, int F, int lq, int lr){
  short8 z = {0,0,0,0,0,0,0,0};
  if (lr < 4) z = *(const short8*)(arr + (F*4 + lq)*32 + lr*8);
  return z;
}

// In-wave gate redistribution + LSTM cell. acc[q] holds gate q for
// (m=reg, j=16p+(lane&15)) in lanes 0..15. After bpermute+select, lane L
// owns cell (m=L>>4, j=16p+(L&15)).
static __device__ __forceinline__ void cell_up(const f32x4* acc, const float* bias,
                                               int lq, int lr, float& cst, float& hval){
  float g[4];
#pragma unroll
  for (int q = 0; q < 4; ++q){
    float t0 = __shfl(acc[q][0], lr);
    float t1 = __shfl(acc[q][1], lr);
    float t2 = __shfl(acc[q][2], lr);
    float t3 = __shfl(acc[q][3], lr);
    float ta = (lq & 1) ? t1 : t0;
    float tb = (lq & 1) ? t3 : t2;
    g[q] = (lq & 2) ? tb : ta;
  }
  float gi = sigm  (g[0] + bias[0]);
  float gf = sigm  (g[1] + bias[1]);
  float gg = tanh_f(g[2] + bias[2]);
  float go = sigm  (g[3] + bias[3]);
  cst  = gf*cst + gi*gg;
  hval = go * tanh_f(cst);
}

// 256 WGs x 512 thr (8 waves, 2/SIMD). WG owns batch rows [4b, 4b+4).
// Wave wv: gemm gm=wv>>2 (0: layer0 computing gates0(i+1); 1: layer1 gates1(i)),
// j-quarter p=wv&3, n-tiles q=0..3 at n=q*64+16p+lr (q = gate index).
// Weights bf16-rounded B-frags in 64 VGPRs. Activations in LDS as separate
// hi/lo frag-ordered arrays, double-buffered; ONE barrier per step.
// act arrs: 0,1 x-hi b0/b1; 2,3 x-lo; 4,5 h0-hi; 6,7 h0-lo; 8,9 h1-hi; 10,11 h1-lo.
extern "C" __global__ void __launch_bounds__(512, 2)
lstm_pipe(const float* __restrict__ x,
          const float* __restrict__ wih0, const float* __restrict__ whh0,
          const float* __restrict__ bih0, const float* __restrict__ bhh0,
          const float* __restrict__ wih1, const float* __restrict__ whh1,
          const float* __restrict__ bih1, const float* __restrict__ bhh1,
          const float* __restrict__ fcw,  const float* __restrict__ fcb,
          float* __restrict__ out)
{
  __shared__ __align__(16) short act[13][256];   // row 12 = pad for stray reads
  __shared__ float fcpart[16];

  const int tid = threadIdx.x;
  const int wv  = tid >> 6;
  const int gm  = wv >> 2;
  const int p   = wv & 3;
  const int ln  = tid & 63;
  const int lq  = ln >> 4;
  const int lr  = ln & 15;
  const int b0  = blockIdx.x << 2;
  const int jc  = (p << 4) + lr;                 // cell/weight j (0..63)
  // cell thread (m=lq, j=jc) h/x store slot:
  const int si  = (((jc>>5)*4 + ((jc>>3)&3))*4 + lq)*8 + (jc&7);

  // ---- one-time: bf16-rounded weight B-frags [op][F][q] = 64 VGPR ----
  short8 W[2][2][4];
  {
    const float* w_op[2] = { gm ? wih1 : wih0, gm ? whh1 : whh0 };
#pragma unroll
    for (int op = 0; op < 2; ++op)
#pragma unroll
      for (int F = 0; F < 2; ++F)
#pragma unroll
        for (int q = 0; q < 4; ++q){
          const float* src = w_op[op] + ((q<<6) + jc)*64 + F*32 + lq*8;
#pragma unroll
          for (int e = 0; e < 8; ++e)
            W[op][F][q][e] = (short)bf16h(__float_as_uint(src[e]));
        }
  }
  float bias[4];
  {
    const float* bi = gm ? bih1 : bih0;
    const float* bh = gm ? bhh1 : bhh0;
#pragma unroll
    for (int q = 0; q < 4; ++q) bias[q] = bi[(q<<6)+jc] + bh[(q<<6)+jc];
  }

  const float* xq = x + (size_t)(b0 + lq)*(TSEQ*64) + jc;

  float cst = 0.f, hval = 0.f, xv = 0.f;

  // ---- prologue ----
  for (int idx = tid; idx < 8*256; idx += 512) act[4 + (idx>>8)][idx & 255] = 0;
  if (gm == 0){
    float x0 = xq[0], x1 = xq[64];
    short h, l;
    fsplit(x0, h, l); act[0][si] = h; act[2][si] = l;   // x(0) -> buf0
    fsplit(x1, h, l); act[1][si] = h; act[3][si] = l;   // x(1) -> buf1
    xv = xq[128];                                        // x(2)
  }
  __syncthreads();

  if (gm == 0){   // gates0(0) = x(0)·Wih0 (h0(-1)=0) -> cell0 -> h0(0) buf0
    f32x4 acc[4] = {{0,0,0,0},{0,0,0,0},{0,0,0,0},{0,0,0,0}};
#pragma unroll
    for (int F = 0; F < 2; ++F){
      short8 ah = ldfrag(&act[0][0], F, lq, lr);
      short8 al = ldfrag(&act[2][0], F, lq, lr);
#pragma unroll
      for (int q = 0; q < 4; ++q) acc[q] = MFMA16(ah, W[0][F][q], acc[q]);
#pragma unroll
      for (int q = 0; q < 4; ++q) acc[q] = MFMA16(al, W[0][F][q], acc[q]);
    }
    cell_up(acc, bias, lq, lr, cst, hval);
    short h, l; fsplit(hval, h, l);
    act[4][si] = h; act[6][si] = l;
  }
  __syncthreads();

  // ---- main loop: ONE barrier per step ----
  for (int i = 0; i < TSEQ; ++i){
    const int cb = i & 1, nb = cb ^ 1;
    if (gm == 1){
      // gates1(i) = h0(i)·Wih1 + h1(i-1)·Whh1
      f32x4 acc[4] = {{0,0,0,0},{0,0,0,0},{0,0,0,0},{0,0,0,0}};
#pragma unroll
      for (int F = 0; F < 2; ++F){
        short8 ah = ldfrag(&act[4+cb][0], F, lq, lr);
        short8 al = ldfrag(&act[6+cb][0], F, lq, lr);
#pragma unroll
        for (int q = 0; q < 4; ++q) acc[q] = MFMA16(ah, W[0][F][q], acc[q]);
#pragma unroll
        for (int q = 0; q < 4; ++q) acc[q] = MFMA16(al, W[0][F][q], acc[q]);
      }
#pragma unroll
      for (int F = 0; F < 2; ++F){
        short8 ah = ldfrag(&act[8+nb][0],  F, lq, lr);
        short8 al = ldfrag(&act[10+nb][0], F, lq, lr);
#pragma unroll
        for (int q = 0; q < 4; ++q) acc[q] = MFMA16(ah, W[1][F][q], acc[q]);
#pragma unroll
        for (int q = 0; q < 4; ++q) acc[q] = MFMA16(al, W[1][F][q], acc[q]);
      }
      cell_up(acc, bias, lq, lr, cst, hval);     // c1, h1(i)
      short h, l; fsplit(hval, h, l);
      act[8+cb][si] = h; act[10+cb][si] = l;
    } else if (i < TSEQ-1){
      // gates0(i+1) = x(i+1)·Wih0 + h0(i)·Whh0
      f32x4 acc[4] = {{0,0,0,0},{0,0,0,0},{0,0,0,0},{0,0,0,0}};
#pragma unroll
      for (int F = 0; F < 2; ++F){
        short8 ah = ldfrag(&act[0+nb][0], F, lq, lr);
        short8 al = ldfrag(&act[2+nb][0], F, lq, lr);
#pragma unroll
        for (int q = 0; q < 4; ++q) acc[q] = MFMA16(ah, W[0][F][q], acc[q]);
#pragma unroll
        for (int q = 0; q < 4; ++q) acc[q] = MFMA16(al, W[0][F][q], acc[q]);
      }
#pragma unroll
      for (int F = 0; F < 2; ++F){
        short8 ah = ldfrag(&act[4+cb][0], F, lq, lr);
        short8 al = ldfrag(&act[6+cb][0], F, lq, lr);
#pragma unroll
        for (int q = 0; q < 4; ++q) acc[q] = MFMA16(ah, W[1][F][q], acc[q]);
#pragma unroll
        for (int q = 0; q < 4; ++q) acc[q] = MFMA16(al, W[1][F][q], acc[q]);
      }
      cell_up(acc, bias, lq, lr, cst, hval);     // c0, h0(i+1)
      short h, l; fsplit(hval, h, l);
      act[4+nb][si] = h; act[6+nb][si] = l;
      if (i < TSEQ-2){                            // stage x(i+2) -> buf cb
        short xh, xl; fsplit(xv, xh, xl);
        act[0+cb][si] = xh; act[2+cb][si] = xl;
      }
      int tn = i + 3; if (tn > TSEQ-1) tn = TSEQ-1;
      xv = xq[tn << 6];                           // prefetch x(i+3)
    }
    __syncthreads();
  }

  // ---- FC head: gemm1 waves hold h1(T-1) for (m=lq, j=jc) ----
  if (gm == 1){
    float v = hval * fcw[jc];
    v += __shfl_xor(v, 1); v += __shfl_xor(v, 2);
    v += __shfl_xor(v, 4); v += __shfl_xor(v, 8);
    if (lr == 0) fcpart[p*4 + lq] = v;
  }
  __syncthreads();
  if (tid < 4)
    out[b0 + tid] = fcpart[tid] + fcpart[4+tid] + fcpart[8+tid] + fcpart[12+tid] + fcb[0];
}

extern "C" void kernel_launch(void* const* d_in, const int* in_sizes, int n_in,
                              void* d_out, int out_size, void* d_ws, size_t ws_size,
                              hipStream_t stream) {
  const float* x    = (const float*)d_in[0];
  const float* wih0 = (const float*)d_in[1];
  const float* whh0 = (const float*)d_in[2];
  const float* bih0 = (const float*)d_in[3];
  const float* bhh0 = (const float*)d_in[4];
  const float* wih1 = (const float*)d_in[5];
  const float* whh1 = (const float*)d_in[6];
  const float* bih1 = (const float*)d_in[7];
  const float* bhh1 = (const float*)d_in[8];
  const float* fcw  = (const float*)d_in[9];
  const float* fcb  = (const float*)d_in[10];
  float* out = (float*)d_out;

  hipLaunchKernelGGL(lstm_pipe, dim3(256), dim3(512), 0, stream,
                     x, wih0, whh0, bih0, bhh0, wih1, whh1, bih1, bhh1, fcw, fcb, out);
}

// Round 5
// 573.373 us; speedup vs baseline: 2.1689x; 1.2598x over previous
//
#include <hip/hip_runtime.h>

#define TSEQ 512

typedef _Float16 half8 __attribute__((ext_vector_type(8)));
typedef __attribute__((ext_vector_type(4))) float f32x4;

#define MFMAH(a,b,c) __builtin_amdgcn_mfma_f32_16x16x32_f16(a,b,c,0,0,0)

static __device__ __forceinline__ float sigm(float x){ return __builtin_amdgcn_rcpf(1.0f + __expf(-x)); }
static __device__ __forceinline__ float tanh_f(float x){ return 1.0f - 2.0f*__builtin_amdgcn_rcpf(__expf(2.0f*x)+1.0f); }

static __device__ __forceinline__ short f2h(float v){
  union { _Float16 h; short s; } u; u.h = (_Float16)v; return u.s;
}

// A-frag masked read: only lanes lr<4 carry real rows (M=4); others zero.
// arr layout: idx(F,kq,m,e) = ((F*4+kq)*4+m)*8+e, k = F*32+kq*8+e.
static __device__ __forceinline__ half8 ldfrag(const short* arr, int F, int lq, int lr){
  half8 z = {0,0,0,0,0,0,0,0};
  if (lr < 4) z = *(const half8*)(arr + (F*4 + lq)*32 + lr*8);
  return z;
}

// In-wave gate redistribution + LSTM cell. acc[q] = gate q for
// (m=reg, j=16p+(lane&15)) in lanes 0..15. After shfl+select, lane L
// owns cell (m=L>>4, j=16p+(L&15)).
static __device__ __forceinline__ void cell_up(const f32x4* acc, const float* bias,
                                               int lq, int lr, float& cst, float& hval){
  float g[4];
#pragma unroll
  for (int q = 0; q < 4; ++q){
    float t0 = __shfl(acc[q][0], lr);
    float t1 = __shfl(acc[q][1], lr);
    float t2 = __shfl(acc[q][2], lr);
    float t3 = __shfl(acc[q][3], lr);
    float ta = (lq & 1) ? t1 : t0;
    float tb = (lq & 1) ? t3 : t2;
    g[q] = (lq & 2) ? tb : ta;
  }
  float gi = sigm  (g[0] + bias[0]);
  float gf = sigm  (g[1] + bias[1]);
  float gg = tanh_f(g[2] + bias[2]);
  float go = sigm  (g[3] + bias[3]);
  cst  = gf*cst + gi*gg;
  hval = go * tanh_f(cst);
}

// 256 WGs x 512 thr (8 waves, 2/SIMD). WG owns batch rows [4b, 4b+4).
// Wave wv: gemm gm=wv>>2 (0: layer0 -> gates0(i+1); 1: layer1 -> gates1(i)),
// j-quarter p=wv&3, n-tiles q=0..3 at n=q*64+16p+lr (q = gate index).
// fp16 1-term: weights as fp16 B-frags in 64 VGPRs; activations fp16 in LDS,
// frag-ordered, double-buffered; ONE barrier per step.
// act arrs: 0,1 x buf0/1; 2,3 h0 buf0/1; 4,5 h1 buf0/1; 6 pad.
extern "C" __global__ void __launch_bounds__(512, 2)
lstm_h16(const float* __restrict__ x,
         const float* __restrict__ wih0, const float* __restrict__ whh0,
         const float* __restrict__ bih0, const float* __restrict__ bhh0,
         const float* __restrict__ wih1, const float* __restrict__ whh1,
         const float* __restrict__ bih1, const float* __restrict__ bhh1,
         const float* __restrict__ fcw,  const float* __restrict__ fcb,
         float* __restrict__ out)
{
  __shared__ __align__(16) short act[7][256];
  __shared__ float fcpart[16];

  const int tid = threadIdx.x;
  const int wv  = tid >> 6;
  const int gm  = wv >> 2;
  const int p   = wv & 3;
  const int ln  = tid & 63;
  const int lq  = ln >> 4;
  const int lr  = ln & 15;
  const int b0  = blockIdx.x << 2;
  const int jc  = (p << 4) + lr;                 // cell/weight j (0..63)
  // cell thread (m=lq, j=jc) h/x store slot:
  const int si  = (((jc>>5)*4 + ((jc>>3)&3))*4 + lq)*8 + (jc&7);

  // ---- one-time: fp16 weight B-frags [op][F][q] = 64 VGPR ----
  half8 W[2][2][4];
  {
    const float* w_op[2] = { gm ? wih1 : wih0, gm ? whh1 : whh0 };
#pragma unroll
    for (int op = 0; op < 2; ++op)
#pragma unroll
      for (int F = 0; F < 2; ++F)
#pragma unroll
        for (int q = 0; q < 4; ++q){
          const float* src = w_op[op] + ((q<<6) + jc)*64 + F*32 + lq*8;
#pragma unroll
          for (int e = 0; e < 8; ++e)
            W[op][F][q][e] = (_Float16)src[e];
        }
  }
  float bias[4];
  {
    const float* bi = gm ? bih1 : bih0;
    const float* bh = gm ? bhh1 : bhh0;
#pragma unroll
    for (int q = 0; q < 4; ++q) bias[q] = bi[(q<<6)+jc] + bh[(q<<6)+jc];
  }

  const float* xq = x + (size_t)(b0 + lq)*(TSEQ*64) + jc;

  float cst = 0.f, hval = 0.f, xv = 0.f;

  // ---- prologue ----
  for (int idx = tid; idx < 4*256; idx += 512) act[2 + (idx>>8)][idx & 255] = 0;
  if (gm == 0){
    act[0][si] = f2h(xq[0]);     // x(0) -> buf0
    act[1][si] = f2h(xq[64]);    // x(1) -> buf1
    xv = xq[128];                // x(2)
  }
  __syncthreads();

  if (gm == 0){   // gates0(0) = x(0)·Wih0 (h0(-1)=0) -> cell0 -> h0(0) buf0
    f32x4 acc[4] = {{0,0,0,0},{0,0,0,0},{0,0,0,0},{0,0,0,0}};
#pragma unroll
    for (int F = 0; F < 2; ++F){
      half8 a = ldfrag(&act[0][0], F, lq, lr);
#pragma unroll
      for (int q = 0; q < 4; ++q) acc[q] = MFMAH(a, W[0][F][q], acc[q]);
    }
    cell_up(acc, bias, lq, lr, cst, hval);
    act[2][si] = f2h(hval);
  }
  __syncthreads();

  // ---- main loop: ONE barrier per step ----
  for (int i = 0; i < TSEQ; ++i){
    const int cb = i & 1, nb = cb ^ 1;
    if (gm == 1){
      // gates1(i) = h0(i)·Wih1 + h1(i-1)·Whh1
      f32x4 acc[4] = {{0,0,0,0},{0,0,0,0},{0,0,0,0},{0,0,0,0}};
#pragma unroll
      for (int F = 0; F < 2; ++F){
        half8 a = ldfrag(&act[2+cb][0], F, lq, lr);
#pragma unroll
        for (int q = 0; q < 4; ++q) acc[q] = MFMAH(a, W[0][F][q], acc[q]);
      }
#pragma unroll
      for (int F = 0; F < 2; ++F){
        half8 a = ldfrag(&act[4+nb][0], F, lq, lr);
#pragma unroll
        for (int q = 0; q < 4; ++q) acc[q] = MFMAH(a, W[1][F][q], acc[q]);
      }
      cell_up(acc, bias, lq, lr, cst, hval);     // c1, h1(i)
      act[4+cb][si] = f2h(hval);
    } else if (i < TSEQ-1){
      // gates0(i+1) = x(i+1)·Wih0 + h0(i)·Whh0
      f32x4 acc[4] = {{0,0,0,0},{0,0,0,0},{0,0,0,0},{0,0,0,0}};
#pragma unroll
      for (int F = 0; F < 2; ++F){
        half8 a = ldfrag(&act[0+nb][0], F, lq, lr);
#pragma unroll
        for (int q = 0; q < 4; ++q) acc[q] = MFMAH(a, W[0][F][q], acc[q]);
      }
#pragma unroll
      for (int F = 0; F < 2; ++F){
        half8 a = ldfrag(&act[2+cb][0], F, lq, lr);
#pragma unroll
        for (int q = 0; q < 4; ++q) acc[q] = MFMAH(a, W[1][F][q], acc[q]);
      }
      cell_up(acc, bias, lq, lr, cst, hval);     // c0, h0(i+1)
      act[2+nb][si] = f2h(hval);
      if (i < TSEQ-2)                             // stage x(i+2) -> buf cb
        act[0+cb][si] = f2h(xv);
      int tn = i + 3; if (tn > TSEQ-1) tn = TSEQ-1;
      xv = xq[tn << 6];                           // prefetch x(i+3)
    }
    __syncthreads();
  }

  // ---- FC head: gemm1 waves hold h1(T-1) for (m=lq, j=jc) ----
  if (gm == 1){
    float v = hval * fcw[jc];
    v += __shfl_xor(v, 1); v += __shfl_xor(v, 2);
    v += __shfl_xor(v, 4); v += __shfl_xor(v, 8);
    if (lr == 0) fcpart[p*4 + lq] = v;
  }
  __syncthreads();
  if (tid < 4)
    out[b0 + tid] = fcpart[tid] + fcpart[4+tid] + fcpart[8+tid] + fcpart[12+tid] + fcb[0];
}

extern "C" void kernel_launch(void* const* d_in, const int* in_sizes, int n_in,
                              void* d_out, int out_size, void* d_ws, size_t ws_size,
                              hipStream_t stream) {
  const float* x    = (const float*)d_in[0];
  const float* wih0 = (const float*)d_in[1];
  const float* whh0 = (const float*)d_in[2];
  const float* bih0 = (const float*)d_in[3];
  const float* bhh0 = (const float*)d_in[4];
  const float* wih1 = (const float*)d_in[5];
  const float* whh1 = (const float*)d_in[6];
  const float* bih1 = (const float*)d_in[7];
  const float* bhh1 = (const float*)d_in[8];
  const float* fcw  = (const float*)d_in[9];
  const float* fcb  = (const float*)d_in[10];
  float* out = (float*)d_out;

  hipLaunchKernelGGL(lstm_h16, dim3(256), dim3(512), 0, stream,
                     x, wih0, whh0, bih0, bhh0, wih1, whh1, bih1, bhh1, fcw, fcb, out);
}

// Round 7
// 456.367 us; speedup vs baseline: 2.7249x; 1.2564x over previous
//
#include <hip/hip_runtime.h>

#define TSEQ 512

typedef _Float16 half8 __attribute__((ext_vector_type(8)));
typedef __attribute__((ext_vector_type(4))) float f32x4;

#define MFMAH(a,b,c) __builtin_amdgcn_mfma_f32_16x16x32_f16(a,b,c,0,0,0)

static __device__ __forceinline__ float sigm(float x){ return __builtin_amdgcn_rcpf(1.0f + __expf(-x)); }
static __device__ __forceinline__ float tanh_f(float x){ return 1.0f - 2.0f*__builtin_amdgcn_rcpf(__expf(2.0f*x)+1.0f); }

static __device__ __forceinline__ short f2h(float v){
  union { _Float16 h; short s; } u; u.h = (_Float16)v; return u.s;
}

// wait lgkmcnt(0) only (vmcnt left alone so x-prefetch stays in flight)
static __device__ __forceinline__ void lds_drain(){
  __builtin_amdgcn_s_waitcnt(0xC07F);
  __asm__ __volatile__("" ::: "memory");
}

// 256 WGs x 512 thr (8 waves, 2/SIMD). WG owns batch rows [4b, 4b+4).
// Wave wv: gemm gm=wv>>2 (0: layer0 -> gates0(i+1); 1: layer1 -> gates1(i)),
// j-quarter p=wv&3, tiles q=0..3 (gate index) at cols q*64+16p+lr.
// fp16 weights as B-frags in 64 VGPRs; bias folded into MFMA C operand.
// Activations fp16 in LDS, frag-ordered, double-buffered, ONE barrier/step.
// Gate redistribution: in-wave LDS roundtrip (masked b128 writes [q][j][m],
// conflict-free b32 reads), no bpermute, no extra barrier.
// act arrs: 0,1 x buf0/1; 2,3 h0 buf0/1; 4,5 h1 buf0/1.
// A-frag offset for lane (lq,lr), chunk F: F*128 + lq*32 + lr*8 (shorts).
extern "C" __global__ void __launch_bounds__(512, 2)
lstm_h16c(const float* __restrict__ x,
          const float* __restrict__ wih0, const float* __restrict__ whh0,
          const float* __restrict__ bih0, const float* __restrict__ bhh0,
          const float* __restrict__ wih1, const float* __restrict__ whh1,
          const float* __restrict__ bih1, const float* __restrict__ bhh1,
          const float* __restrict__ fcw,  const float* __restrict__ fcb,
          float* __restrict__ out)
{
  __shared__ __align__(16) short act[6][256];
  __shared__ __align__(16) float gbuf[2][1024];   // [gemm][q*256 + j*4 + m]
  __shared__ float fcpart[16];

  const int tid = threadIdx.x;
  const int wv  = tid >> 6;
  const int gm  = wv >> 2;
  const int p   = wv & 3;
  const int ln  = tid & 63;
  const int lq  = ln >> 4;
  const int lr  = ln & 15;
  const int b0  = blockIdx.x << 2;
  const int jc  = (p << 4) + lr;                 // j (0..63): gemm col / cell col
  // h/x staging slot for cell thread (k=jc, m=lq):
  const int si  = (((jc>>5)*4 + ((jc>>3)&3))*4 + lq)*8 + (jc&7);
  // A-frag read offset for chunk F=0 (F adds +128): shorts
  const int foff = lq*32 + lr*8;
  float* const gme = &gbuf[gm][0];
  const bool wlane = (lq == 0);

  // ---- one-time: fp16 weight B-frags [op][F][q] = 64 VGPR ----
  half8 W[2][2][4];
  {
    const float* w_op[2] = { gm ? wih1 : wih0, gm ? whh1 : whh0 };
#pragma unroll
    for (int op = 0; op < 2; ++op)
#pragma unroll
      for (int F = 0; F < 2; ++F)
#pragma unroll
        for (int q = 0; q < 4; ++q){
          const float* src = w_op[op] + ((q<<6) + jc)*64 + F*32 + lq*8;
#pragma unroll
          for (int e = 0; e < 8; ++e)
            W[op][F][q][e] = (_Float16)src[e];
        }
  }
  // bias in C operand: Bq[q] = broadcast(bias_q(jc))
  f32x4 Bq[4];
  {
    const float* bi = gm ? bih1 : bih0;
    const float* bh = gm ? bhh1 : bhh0;
#pragma unroll
    for (int q = 0; q < 4; ++q){
      float b = bi[(q<<6)+jc] + bh[(q<<6)+jc];
      Bq[q][0] = b; Bq[q][1] = b; Bq[q][2] = b; Bq[q][3] = b;
    }
  }

  const float* xq = x + (size_t)(b0 + lq)*(TSEQ*64) + jc;

  float cst = 0.f, hval = 0.f, xv = 0.f;
  half8 aF[4];   // persistent frag regs (masked loads leave lr>=4 lanes stale: harmless rows 4-15)
#pragma unroll
  for (int f = 0; f < 4; ++f) aF[f] = (half8){0,0,0,0,0,0,0,0};

  // ---- prologue ----
  for (int idx = tid; idx < 2*256; idx += 512) act[4 + (idx>>8)][idx & 255] = 0;
  if (gm == 0){
    act[0][si] = f2h(xq[0]);     // x(0) -> buf0
    act[1][si] = f2h(xq[64]);    // x(1) -> buf1
    xv = xq[128];                // x(2)
  }
  __syncthreads();

  if (gm == 0){   // gates0(0) = x(0)·Wih0 + bias (h0(-1)=0) -> cell0 -> h0(0) buf0
    if (lr < 4){
      aF[0] = *(const half8*)(&act[0][0] + foff);
      aF[1] = *(const half8*)(&act[0][0] + foff + 128);
    }
    f32x4 acc[4];
#pragma unroll
    for (int q = 0; q < 4; ++q){
      acc[q] = MFMAH(aF[0], W[0][0][q], Bq[q]);
      acc[q] = MFMAH(aF[1], W[0][1][q], acc[q]);
    }
    if (wlane){
#pragma unroll
      for (int q = 0; q < 4; ++q) *(f32x4*)&gme[q*256 + jc*4] = acc[q];
    }
    lds_drain();
    float gi = sigm  (gme[0*256 + jc*4 + lq]);
    float gf = sigm  (gme[1*256 + jc*4 + lq]);
    float gg = tanh_f(gme[2*256 + jc*4 + lq]);
    float go = sigm  (gme[3*256 + jc*4 + lq]);
    cst  = gf*cst + gi*gg;
    hval = go * tanh_f(cst);
    act[2][si] = f2h(hval);
  }
  __syncthreads();

  // ---- main loops: divergent by gemm, ONE barrier per iteration each ----
  if (gm == 1){
#pragma unroll 2
    for (int i = 0; i < TSEQ; ++i){
      const int cb = i & 1, nb = cb ^ 1;
      // gates1(i) = h0(i)·Wih1 + h1(i-1)·Whh1 + bias
      if (lr < 4){
        aF[0] = *(const half8*)(&act[2+cb][0] + foff);
        aF[1] = *(const half8*)(&act[2+cb][0] + foff + 128);
        aF[2] = *(const half8*)(&act[4+nb][0] + foff);
        aF[3] = *(const half8*)(&act[4+nb][0] + foff + 128);
      }
      f32x4 acc[4];
#pragma unroll
      for (int q = 0; q < 4; ++q){
        acc[q] = MFMAH(aF[0], W[0][0][q], Bq[q]);
        acc[q] = MFMAH(aF[1], W[0][1][q], acc[q]);
        acc[q] = MFMAH(aF[2], W[1][0][q], acc[q]);
        acc[q] = MFMAH(aF[3], W[1][1][q], acc[q]);
      }
      if (wlane){
#pragma unroll
        for (int q = 0; q < 4; ++q) *(f32x4*)&gme[q*256 + jc*4] = acc[q];
      }
      lds_drain();
      float gi = sigm  (gme[0*256 + jc*4 + lq]);
      float gf = sigm  (gme[1*256 + jc*4 + lq]);
      float gg = tanh_f(gme[2*256 + jc*4 + lq]);
      float go = sigm  (gme[3*256 + jc*4 + lq]);
      cst  = gf*cst + gi*gg;
      hval = go * tanh_f(cst);
      act[4+cb][si] = f2h(hval);     // h1(i)
      __syncthreads();
    }
  } else {
#pragma unroll 2
    for (int i = 0; i < TSEQ; ++i){
      const int cb = i & 1, nb = cb ^ 1;
      if (i < TSEQ-1){
        // gates0(i+1) = x(i+1)·Wih0 + h0(i)·Whh0 + bias
        if (lr < 4){
          aF[0] = *(const half8*)(&act[0+nb][0] + foff);
          aF[1] = *(const half8*)(&act[0+nb][0] + foff + 128);
          aF[2] = *(const half8*)(&act[2+cb][0] + foff);
          aF[3] = *(const half8*)(&act[2+cb][0] + foff + 128);
        }
        f32x4 acc[4];
#pragma unroll
        for (int q = 0; q < 4; ++q){
          acc[q] = MFMAH(aF[0], W[0][0][q], Bq[q]);
          acc[q] = MFMAH(aF[1], W[0][1][q], acc[q]);
          acc[q] = MFMAH(aF[2], W[1][0][q], acc[q]);
          acc[q] = MFMAH(aF[3], W[1][1][q], acc[q]);
        }
        if (wlane){
#pragma unroll
          for (int q = 0; q < 4; ++q) *(f32x4*)&gme[q*256 + jc*4] = acc[q];
        }
        lds_drain();
        float gi = sigm  (gme[0*256 + jc*4 + lq]);
        float gf = sigm  (gme[1*256 + jc*4 + lq]);
        float gg = tanh_f(gme[2*256 + jc*4 + lq]);
        float go = sigm  (gme[3*256 + jc*4 + lq]);
        cst  = gf*cst + gi*gg;
        hval = go * tanh_f(cst);
        act[2+nb][si] = f2h(hval);   // h0(i+1)
        if (i < TSEQ-2) act[0+cb][si] = f2h(xv);   // stage x(i+2)
        int tn = i + 3; if (tn > TSEQ-1) tn = TSEQ-1;
        xv = xq[tn << 6];            // prefetch x(i+3)
      }
      __syncthreads();
    }
  }

  // ---- FC head: gemm1 waves hold h1(T-1) for (m=lq, j=jc) ----
  if (gm == 1){
    float v = hval * fcw[jc];
    v += __shfl_xor(v, 1); v += __shfl_xor(v, 2);
    v += __shfl_xor(v, 4); v += __shfl_xor(v, 8);
    if (lr == 0) fcpart[p*4 + lq] = v;
  }
  __syncthreads();
  if (tid < 4)
    out[b0 + tid] = fcpart[tid] + fcpart[4+tid] + fcpart[8+tid] + fcpart[12+tid] + fcb[0];
}

extern "C" void kernel_launch(void* const* d_in, const int* in_sizes, int n_in,
                              void* d_out, int out_size, void* d_ws, size_t ws_size,
                              hipStream_t stream) {
  const float* x    = (const float*)d_in[0];
  const float* wih0 = (const float*)d_in[1];
  const float* whh0 = (const float*)d_in[2];
  const float* bih0 = (const float*)d_in[3];
  const float* bhh0 = (const float*)d_in[4];
  const float* wih1 = (const float*)d_in[5];
  const float* whh1 = (const float*)d_in[6];
  const float* bih1 = (const float*)d_in[7];
  const float* bhh1 = (const float*)d_in[8];
  const float* fcw  = (const float*)d_in[9];
  const float* fcb  = (const float*)d_in[10];
  float* out = (float*)d_out;

  hipLaunchKernelGGL(lstm_h16c, dim3(256), dim3(512), 0, stream,
                     x, wih0, whh0, bih0, bhh0, wih1, whh1, bih1, bhh1, fcw, fcb, out);
}